// Round 5
// baseline (166.553 us; speedup 1.0000x reference)
//
#include <hip/hip_runtime.h>
#include <hip/hip_cooperative_groups.h>
#include <math.h>

namespace cg = cooperative_groups;

// Problem constants: N=8192 nodes, IN=512, OUT=8192, HEADS=1.
#define NN    8192
#define INC   512
#define GRID  256
#define BLOCK 1024

// ws layout (floats):
//   deg[NN] adv[NN] t[INC] u[INC] scal[8] s[NN]   <- zeroed each call
//   xu[NN] parts[GRID]                            <- written directly
#define WS_ZERO (3 * NN + 2 * INC + 8)

__global__ __launch_bounds__(BLOCK) void fused_kernel(
        const float* __restrict__ x, const int* __restrict__ row,
        const int* __restrict__ col, int E,
        const float* __restrict__ weight, const float* __restrict__ bias,
        const float* __restrict__ att, const float* __restrict__ lin_w,
        const float* __restrict__ lin_b, float* __restrict__ ws,
        float* __restrict__ out) {
    cg::grid_group grid = cg::this_grid();
    const int b = blockIdx.x, tid = threadIdx.x;

    float* deg   = ws;                         // [NN] (raw degree; rsqrt applied on read)
    float* adv   = ws + NN;                    // [NN]
    float* t     = ws + 2 * NN;                // [INC]
    float* u     = ws + 2 * NN + INC;          // [INC]
    float* scal  = ws + 2 * NN + 2 * INC;      // [8]: 0=c0
    float* s     = ws + 2 * NN + 2 * INC + 8;  // [NN]
    float* xu    = ws + 3 * NN + 2 * INC + 8;  // [NN]
    float* parts = ws + 4 * NN + 2 * INC + 8;  // [GRID] scal1 block partials

    __shared__ float4 lds4[BLOCK];             // 16 KB, reused per phase
    float* ldss = (float*)lds4;

    // ---------------- P0: zero accumulators (ws poisoned 0xAA by harness) ---
    for (int i = b * BLOCK + tid; i < WS_ZERO; i += GRID * BLOCK) ws[i] = 0.f;
    grid.sync();

    // ---------------- P1: deg || u = lin_w^T a1 || c0 = lin_b.a1 ------------
    if (b < 64) {                              // deg[row[e]] += 1
        const int estep = 64 * BLOCK * 4;
        for (int i0 = (b * BLOCK + tid) * 4; i0 < E; i0 += estep) {
            if (i0 + 3 < E) {
                int4 r = *(const int4*)(row + i0);
                atomicAdd(&deg[r.x], 1.f); atomicAdd(&deg[r.y], 1.f);
                atomicAdd(&deg[r.z], 1.f); atomicAdd(&deg[r.w], 1.f);
            } else {
                for (int e = i0; e < E; ++e) atomicAdd(&deg[row[e]], 1.f);
            }
        }
    } else if (b < 192) {                      // u: 128 blocks x 64 rows
        const int r0 = (b - 64) * 64;
        const int c4 = tid & 127, rg = tid >> 7;
        float4 acc = {0.f, 0.f, 0.f, 0.f};
        #pragma unroll
        for (int it = 0; it < 8; ++it) {
            int r = r0 + rg * 8 + it;
            float w = att[r];
            float4 v = ((const float4*)(lin_w + (size_t)r * INC))[c4];
            acc.x += w * v.x; acc.y += w * v.y; acc.z += w * v.z; acc.w += w * v.w;
        }
        lds4[tid] = acc;
        __syncthreads();
        #pragma unroll
        for (int off = 4; off > 0; off >>= 1) {
            if (rg < off) {
                float4 o = lds4[(rg + off) * 128 + c4];
                float4 m = lds4[tid];
                m.x += o.x; m.y += o.y; m.z += o.z; m.w += o.w;
                lds4[tid] = m;
            }
            __syncthreads();
        }
        if (rg == 0) {
            float4 a = lds4[c4];
            atomicAdd(&u[4 * c4 + 0], a.x); atomicAdd(&u[4 * c4 + 1], a.y);
            atomicAdd(&u[4 * c4 + 2], a.z); atomicAdd(&u[4 * c4 + 3], a.w);
        }
    } else if (b == 192) {                     // c0
        float v = 0.f;
        for (int i = tid; i < NN; i += BLOCK) v += lin_b[i] * att[i];
        ldss[tid] = v;
        __syncthreads();
        #pragma unroll
        for (int off = 512; off > 0; off >>= 1) {
            if (tid < off) ldss[tid] += ldss[tid + off];
            __syncthreads();
        }
        if (tid == 0) scal[0] = ldss[0];
    }
    grid.sync();

    // ---------------- P2: adv || t = x^T dinv || xu = x.u --------------------
    if (b < 64) {                              // adv[row] += rsqrt(deg[col])
        const int estep = 64 * BLOCK * 4;
        for (int i0 = (b * BLOCK + tid) * 4; i0 < E; i0 += estep) {
            if (i0 + 3 < E) {
                int4 r = *(const int4*)(row + i0);
                int4 c = *(const int4*)(col + i0);
                atomicAdd(&adv[r.x], 1.f / sqrtf(deg[c.x]));
                atomicAdd(&adv[r.y], 1.f / sqrtf(deg[c.y]));
                atomicAdd(&adv[r.z], 1.f / sqrtf(deg[c.z]));
                atomicAdd(&adv[r.w], 1.f / sqrtf(deg[c.w]));
            } else {
                for (int e = i0; e < E; ++e)
                    atomicAdd(&adv[row[e]], 1.f / sqrtf(deg[col[e]]));
            }
        }
    } else if (b < 128) {                      // t: 64 blocks x 128 rows
        const int r0 = (b - 64) * 128;
        const int c4 = tid & 127, rg = tid >> 7;
        float4 acc = {0.f, 0.f, 0.f, 0.f};
        #pragma unroll
        for (int it = 0; it < 16; ++it) {
            int r = r0 + rg * 16 + it;
            float w = 1.f / sqrtf(deg[r]);
            float4 v = ((const float4*)(x + (size_t)r * INC))[c4];
            acc.x += w * v.x; acc.y += w * v.y; acc.z += w * v.z; acc.w += w * v.w;
        }
        lds4[tid] = acc;
        __syncthreads();
        #pragma unroll
        for (int off = 4; off > 0; off >>= 1) {
            if (rg < off) {
                float4 o = lds4[(rg + off) * 128 + c4];
                float4 m = lds4[tid];
                m.x += o.x; m.y += o.y; m.z += o.z; m.w += o.w;
                lds4[tid] = m;
            }
            __syncthreads();
        }
        if (rg == 0) {
            float4 a = lds4[c4];
            atomicAdd(&t[4 * c4 + 0], a.x); atomicAdd(&t[4 * c4 + 1], a.y);
            atomicAdd(&t[4 * c4 + 2], a.z); atomicAdd(&t[4 * c4 + 3], a.w);
        }
    } else {                                   // xu: 128 blocks x 64 rows
        if (tid < 128) lds4[tid] = ((const float4*)u)[tid];
        __syncthreads();
        const int wave = tid >> 6, lane = tid & 63;
        const int i0 = (b - 128) * 64 + wave * 4;
        #pragma unroll
        for (int r = 0; r < 4; ++r) {
            const float4* __restrict__ xr = (const float4*)(x + (size_t)(i0 + r) * INC);
            float4 v0 = xr[lane],      u0 = lds4[lane];
            float4 v1 = xr[lane + 64], u1 = lds4[lane + 64];
            float a = v0.x * u0.x + v0.y * u0.y + v0.z * u0.z + v0.w * u0.w
                    + v1.x * u1.x + v1.y * u1.y + v1.z * u1.z + v1.w * u1.w;
            #pragma unroll
            for (int off = 32; off > 0; off >>= 1) a += __shfl_down(a, off);
            if (lane == 0) xu[i0 + r] = a;
        }
    }
    grid.sync();

    // ---------------- P3: s = t.W  (+ per-block scal1 partial) ---------------
    {
        const int kb = b & 7, cb = b >> 3;             // k-chunk 1024, c-chunk 16
        const int ks = tid & 255, csub = tid >> 8;     // 4 c's per thread
        const int k = kb * 1024 + ks * 4;
        const int cbase = cb * 16 + csub * 4;
        const float* __restrict__ wp = weight + (size_t)cbase * NN + k;
        float4 acc = {0.f, 0.f, 0.f, 0.f};
        #pragma unroll
        for (int c = 0; c < 4; ++c) {
            float tc = t[cbase + c];
            float4 v = *(const float4*)(wp + (size_t)c * NN);
            acc.x += tc * v.x; acc.y += tc * v.y; acc.z += tc * v.z; acc.w += tc * v.w;
        }
        lds4[tid] = acc;
        __syncthreads();
        float p = 0.f;
        if (csub == 0) {
            float4 a = lds4[tid], o1 = lds4[tid + 256], o2 = lds4[tid + 512], o3 = lds4[tid + 768];
            a.x += o1.x + o2.x + o3.x; a.y += o1.y + o2.y + o3.y;
            a.z += o1.z + o2.z + o3.z; a.w += o1.w + o2.w + o3.w;
            atomicAdd(&s[k + 0], a.x); atomicAdd(&s[k + 1], a.y);
            atomicAdd(&s[k + 2], a.z); atomicAdd(&s[k + 3], a.w);
            float4 a2 = *(const float4*)(att + NN + k);
            p = a.x * a2.x + a.y * a2.y + a.z * a2.z + a.w * a2.w;
        }
        #pragma unroll
        for (int off = 32; off > 0; off >>= 1) p += __shfl_down(p, off);
        __syncthreads();                      // done reading lds4 before scalar reuse
        if ((tid & 63) == 0) ldss[tid >> 6] = p;
        __syncthreads();
        if (tid == 0) {
            float sum = 0.f;
            #pragma unroll
            for (int w = 0; w < 16; ++w) sum += ldss[w];
            parts[b] = sum;                   // block partial of scal1 = s.a2
        }
    }
    grid.sync();

    // ---------------- P4: scal1/scal2 (redundant per block) + out ------------
    {
        // scal1 = sum of 256 block partials
        ldss[tid] = (tid < GRID) ? parts[tid] : 0.f;
        __syncthreads();
        #pragma unroll
        for (int off = 512; off > 0; off >>= 1) {
            if (tid < off) ldss[tid] += ldss[tid + off];
            __syncthreads();
        }
        const float scal1 = ldss[0];
        const float c0 = scal[0];
        __syncthreads();

        // scal2 = sum_i s[i] * leaky_relu(xu[i] + c0 + adv[i]*scal1, 0.2)
        float acc = 0.f;
        for (int i = tid; i < NN; i += BLOCK) {
            float a  = xu[i] + c0 + adv[i] * scal1;
            float lr = a > 0.f ? a : 0.2f * a;
            acc += lr * s[i];
        }
        ldss[tid] = acc;
        __syncthreads();
        #pragma unroll
        for (int off = 512; off > 0; off >>= 1) {
            if (tid < off) ldss[tid] += ldss[tid + off];
            __syncthreads();
        }
        const float scal2 = ldss[0];

        if (tid < 32) {                       // each block owns a 32-elem out slice
            int i = b * 32 + tid;
            float v = adv[i] * scal2 + bias[i];
            out[i] = v > 0.f ? v : 0.f;
        }
    }
}

// ---------------------------------------------------------------------------
extern "C" void kernel_launch(void* const* d_in, const int* in_sizes, int n_in,
                              void* d_out, int out_size, void* d_ws, size_t ws_size,
                              hipStream_t stream) {
    const float* x      = (const float*)d_in[0];   // [8192, 512]
    const int*   eidx   = (const int*)d_in[1];     // [2, E]
    const float* weight = (const float*)d_in[2];   // [512, 8192]
    const float* bias   = (const float*)d_in[3];   // [8192]
    const float* att    = (const float*)d_in[4];   // [16384]
    const float* lin_w  = (const float*)d_in[5];   // [8192, 512]
    const float* lin_b  = (const float*)d_in[6];   // [8192]

    int E = in_sizes[1] / 2;
    const int* row = eidx;
    const int* col = eidx + E;
    float* ws  = (float*)d_ws;
    float* out = (float*)d_out;

    void* args[] = {(void*)&x, (void*)&row, (void*)&col, (void*)&E,
                    (void*)&weight, (void*)&bias, (void*)&att,
                    (void*)&lin_w, (void*)&lin_b, (void*)&ws, (void*)&out};
    hipLaunchCooperativeKernel((void*)fused_kernel, dim3(GRID), dim3(BLOCK),
                               args, 0, stream);
}

// Round 6
// 81.989 us; speedup vs baseline: 2.0314x; 2.0314x over previous
//
#include <hip/hip_runtime.h>
#include <math.h>

// Problem constants: N=8192 nodes, IN=512, OUT=8192, HEADS=1.
#define NN  8192
#define INC 512

// ws layout (floats):
//   deg8[8*NN] adv8[8*NN] t[512] u[512] scal[8] s[NN]   <- zeroed (K0)
//   dinv[NN] xu[NN]                                     <- exact-written
#define OFF_DEG8 0
#define OFF_ADV8 (8 * NN)
#define OFF_T    (16 * NN)
#define OFF_U    (16 * NN + INC)
#define OFF_SCAL (16 * NN + 2 * INC)
#define OFF_S    (16 * NN + 2 * INC + 8)
#define OFF_DINV (17 * NN + 2 * INC + 8)
#define OFF_XU   (18 * NN + 2 * INC + 8)
#define WS_ZERO  (17 * NN + 2 * INC + 8)   // 140296 floats, /4 = 35074 float4

// ---------------------------------------------------------------------------
// K0: zero accumulators (float4, one shot: 64 blocks x 1024 threads >= 35074)
__global__ __launch_bounds__(1024) void k0_zero(float4* __restrict__ ws4) {
    int i = blockIdx.x * 1024 + threadIdx.x;
    if (i < WS_ZERO / 4) ws4[i] = make_float4(0.f, 0.f, 0.f, 0.f);
}

// ---------------------------------------------------------------------------
// K1: blocks 0..127  -> u = lin_w^T a1  (64 rows each, float4, LDS tree)
//     blocks 128..255-> deg8 histogram: deg8[(b&7)*NN + row[e]] += 1
//                       (copy index == b%8 == round-robin XCD -> L2-local)
__global__ __launch_bounds__(1024) void k1_u_deg(
        const float* __restrict__ lin_w, const float* __restrict__ att,
        const int* __restrict__ row, int E, float* __restrict__ ws) {
    float* deg8 = ws + OFF_DEG8;
    float* u    = ws + OFF_U;
    const int b = blockIdx.x, tid = threadIdx.x;

    if (b >= 128) {                          // deg histogram, int2 edge loads
        const int cp = b & 7;
        float* __restrict__ mydeg = deg8 + (size_t)cp * NN;
        const int stride = 128 * 1024 * 2;
        for (int i0 = ((b - 128) * 1024 + tid) * 2; i0 < E; i0 += stride) {
            if (i0 + 1 < E) {
                int2 r = *(const int2*)(row + i0);
                atomicAdd(&mydeg[r.x], 1.f);
                atomicAdd(&mydeg[r.y], 1.f);
            } else {
                atomicAdd(&mydeg[row[i0]], 1.f);
            }
        }
        return;
    }

    __shared__ float4 lds4[1024];
    const int r0 = b * 64;
    const int c4 = tid & 127, rg = tid >> 7;
    float4 acc = {0.f, 0.f, 0.f, 0.f};
    #pragma unroll
    for (int it = 0; it < 8; ++it) {
        int r = r0 + rg * 8 + it;
        float w = att[r];
        float4 v = ((const float4*)(lin_w + (size_t)r * INC))[c4];
        acc.x += w * v.x; acc.y += w * v.y; acc.z += w * v.z; acc.w += w * v.w;
    }
    lds4[tid] = acc;
    __syncthreads();
    #pragma unroll
    for (int off = 4; off > 0; off >>= 1) {
        if (rg < off) {
            float4 o = lds4[(rg + off) * 128 + c4];
            float4 m = lds4[tid];
            m.x += o.x; m.y += o.y; m.z += o.z; m.w += o.w;
            lds4[tid] = m;
        }
        __syncthreads();
    }
    if (rg == 0) {
        float4 a = lds4[c4];
        atomicAdd(&u[4 * c4 + 0], a.x); atomicAdd(&u[4 * c4 + 1], a.y);
        atomicAdd(&u[4 * c4 + 2], a.z); atomicAdd(&u[4 * c4 + 3], a.w);
    }
}

// ---------------------------------------------------------------------------
// K1.5: dinv[i] = rsqrt(sum_k deg8[k][i])     (8 blocks x 1024)
__global__ __launch_bounds__(1024) void k15_dinv(float* __restrict__ ws) {
    const float* deg8 = ws + OFF_DEG8;
    float* dinv = ws + OFF_DINV;
    int i = blockIdx.x * 1024 + threadIdx.x;
    if (i < NN) {
        float d = 0.f;
        #pragma unroll
        for (int k = 0; k < 8; ++k) d += deg8[k * NN + i];
        dinv[i] = 1.f / sqrtf(d);
    }
}

// ---------------------------------------------------------------------------
// K2: blocks 0..127  -> adv8 histogram: adv8[(b&7)*NN + row[e]] += dinv[col[e]]
//     blocks 128..255-> fused single pass over x (64 rows each):
//                         t[c]  += dinv[r] * x[r,c]   (column reduction)
//                         xu[r]  = x[r,:] . u         (row dot)
__global__ __launch_bounds__(1024) void k2_adv_t_xu(
        const float* __restrict__ x, const int* __restrict__ row,
        const int* __restrict__ col, int E, float* __restrict__ ws) {
    float* adv8 = ws + OFF_ADV8;
    const float* dinv = ws + OFF_DINV;
    const float* u    = ws + OFF_U;
    float* t  = ws + OFF_T;
    float* xu = ws + OFF_XU;
    const int b = blockIdx.x, tid = threadIdx.x;

    if (b < 128) {                           // adv histogram (dinv is 32KB: L1-hot)
        const int cp = b & 7;
        float* __restrict__ myadv = adv8 + (size_t)cp * NN;
        const int stride = 128 * 1024 * 2;
        for (int i0 = (b * 1024 + tid) * 2; i0 < E; i0 += stride) {
            if (i0 + 1 < E) {
                int2 r = *(const int2*)(row + i0);
                int2 c = *(const int2*)(col + i0);
                atomicAdd(&myadv[r.x], dinv[c.x]);
                atomicAdd(&myadv[r.y], dinv[c.y]);
            } else {
                atomicAdd(&myadv[row[i0]], dinv[col[i0]]);
            }
        }
        return;
    }

    __shared__ float4 u4[128];
    __shared__ float dinv_l[64];
    __shared__ float xured[8][8][2];         // [rg][it][wave-in-rowgroup]
    __shared__ float4 lds4[1024];
    const int r0 = (b - 128) * 64;
    if (tid < 128) u4[tid] = ((const float4*)u)[tid];
    if (tid < 64)  dinv_l[tid] = dinv[r0 + tid];
    __syncthreads();

    const int c4 = tid & 127, rg = tid >> 7;   // 8 row-groups x 128 cols(f4)
    const int lane = tid & 63;
    float4 accT = {0.f, 0.f, 0.f, 0.f};
    float xup[8];
    #pragma unroll
    for (int it = 0; it < 8; ++it) {
        int rl = rg + it * 8;                  // local row 0..63
        float4 v = ((const float4*)(x + (size_t)(r0 + rl) * INC))[c4];
        float w = dinv_l[rl];
        accT.x += w * v.x; accT.y += w * v.y; accT.z += w * v.z; accT.w += w * v.w;
        float4 uu = u4[c4];
        xup[it] = v.x * uu.x + v.y * uu.y + v.z * uu.z + v.w * uu.w;
    }
    // xu: reduce each row over its 128 threads (2 waves)
    #pragma unroll
    for (int it = 0; it < 8; ++it) {
        float a = xup[it];
        #pragma unroll
        for (int off = 32; off > 0; off >>= 1) a += __shfl_down(a, off);
        if (lane == 0) xured[rg][it][(tid >> 6) & 1] = a;
    }
    // t: LDS tree over row-groups
    lds4[tid] = accT;
    __syncthreads();
    if (tid < 64) {
        int rg2 = tid >> 3, it2 = tid & 7;
        xu[r0 + rg2 + it2 * 8] = xured[rg2][it2][0] + xured[rg2][it2][1];
    }
    #pragma unroll
    for (int off = 4; off > 0; off >>= 1) {
        if (rg < off) {
            float4 o = lds4[(rg + off) * 128 + c4];
            float4 m = lds4[tid];
            m.x += o.x; m.y += o.y; m.z += o.z; m.w += o.w;
            lds4[tid] = m;
        }
        __syncthreads();
    }
    if (rg == 0) {
        float4 a = lds4[c4];
        atomicAdd(&t[4 * c4 + 0], a.x); atomicAdd(&t[4 * c4 + 1], a.y);
        atomicAdd(&t[4 * c4 + 2], a.z); atomicAdd(&t[4 * c4 + 3], a.w);
    }
}

// ---------------------------------------------------------------------------
// K3: blocks 0..255 -> s = t.W (kb=b&7: k-chunk 1024, cb=b>>3: c-chunk 16)
//                      + scal[1] += partial of dot(s, a2)
//     block 256     -> scal[0] = c0 = lin_b . a1
__global__ __launch_bounds__(1024) void k3_s_c0(
        const float* __restrict__ weight, const float* __restrict__ att,
        const float* __restrict__ lin_b, float* __restrict__ ws) {
    const float* t = ws + OFF_T;
    float* scal = ws + OFF_SCAL;
    float* s    = ws + OFF_S;
    const int b = blockIdx.x, tid = threadIdx.x;
    __shared__ float4 lds4[1024];
    float* ldss = (float*)lds4;

    if (b == 256) {                          // c0
        float v = 0.f;
        for (int i = tid; i < NN; i += 1024) v += lin_b[i] * att[i];
        ldss[tid] = v;
        __syncthreads();
        #pragma unroll
        for (int off = 512; off > 0; off >>= 1) {
            if (tid < off) ldss[tid] += ldss[tid + off];
            __syncthreads();
        }
        if (tid == 0) scal[0] = ldss[0];
        return;
    }

    const int kb = b & 7, cb = b >> 3;
    const int ks = tid & 255, csub = tid >> 8;   // 4 c's per thread
    const int k = kb * 1024 + ks * 4;
    const int cbase = cb * 16 + csub * 4;
    const float* __restrict__ wp = weight + (size_t)cbase * NN + k;
    float4 acc = {0.f, 0.f, 0.f, 0.f};
    #pragma unroll
    for (int c = 0; c < 4; ++c) {
        float tc = t[cbase + c];
        float4 v = *(const float4*)(wp + (size_t)c * NN);
        acc.x += tc * v.x; acc.y += tc * v.y; acc.z += tc * v.z; acc.w += tc * v.w;
    }
    lds4[tid] = acc;
    __syncthreads();
    float p = 0.f;
    if (csub == 0) {
        float4 a = lds4[tid], o1 = lds4[tid + 256], o2 = lds4[tid + 512], o3 = lds4[tid + 768];
        a.x += o1.x + o2.x + o3.x; a.y += o1.y + o2.y + o3.y;
        a.z += o1.z + o2.z + o3.z; a.w += o1.w + o2.w + o3.w;
        atomicAdd(&s[k + 0], a.x); atomicAdd(&s[k + 1], a.y);
        atomicAdd(&s[k + 2], a.z); atomicAdd(&s[k + 3], a.w);
        float4 a2 = *(const float4*)(att + NN + k);
        p = a.x * a2.x + a.y * a2.y + a.z * a2.z + a.w * a2.w;
    }
    #pragma unroll
    for (int off = 32; off > 0; off >>= 1) p += __shfl_down(p, off);
    __syncthreads();
    if ((tid & 63) == 0) ldss[tid >> 6] = p;
    __syncthreads();
    if (tid == 0) {
        float sum = 0.f;
        #pragma unroll
        for (int w = 0; w < 16; ++w) sum += ldss[w];
        atomicAdd(&scal[1], sum);
    }
}

// ---------------------------------------------------------------------------
// K4 (single block): adv[i] = sum_k adv8[k][i];
//   scal2 = sum_i s[i] * leaky_relu(xu[i] + c0 + adv[i]*scal1, 0.2)
//   out[i] = relu(adv[i]*scal2 + bias[i])     (adv kept in registers)
__global__ __launch_bounds__(1024) void k4_out(
        const float* __restrict__ bias, const float* __restrict__ ws,
        float* __restrict__ out) {
    const float* adv8 = ws + OFF_ADV8;
    const float* scal = ws + OFF_SCAL;
    const float* s    = ws + OFF_S;
    const float* xu   = ws + OFF_XU;
    const int tid = threadIdx.x;
    __shared__ float red[1024];

    const float c0 = scal[0], s1 = scal[1];
    float advv[8];
    float acc = 0.f;
    #pragma unroll
    for (int m = 0; m < 8; ++m) {
        int i = tid + m * 1024;
        float a8 = 0.f;
        #pragma unroll
        for (int k = 0; k < 8; ++k) a8 += adv8[k * NN + i];
        advv[m] = a8;
        float a  = xu[i] + c0 + a8 * s1;
        float lr = a > 0.f ? a : 0.2f * a;
        acc += lr * s[i];
    }
    red[tid] = acc;
    __syncthreads();
    #pragma unroll
    for (int off = 512; off > 0; off >>= 1) {
        if (tid < off) red[tid] += red[tid + off];
        __syncthreads();
    }
    const float scal2 = red[0];
    #pragma unroll
    for (int m = 0; m < 8; ++m) {
        int i = tid + m * 1024;
        float v = advv[m] * scal2 + bias[i];
        out[i] = v > 0.f ? v : 0.f;
    }
}

// ---------------------------------------------------------------------------
extern "C" void kernel_launch(void* const* d_in, const int* in_sizes, int n_in,
                              void* d_out, int out_size, void* d_ws, size_t ws_size,
                              hipStream_t stream) {
    const float* x      = (const float*)d_in[0];   // [8192, 512]
    const int*   eidx   = (const int*)d_in[1];     // [2, E]
    const float* weight = (const float*)d_in[2];   // [512, 8192]
    const float* bias   = (const float*)d_in[3];   // [8192]
    const float* att    = (const float*)d_in[4];   // [16384]
    const float* lin_w  = (const float*)d_in[5];   // [8192, 512]
    const float* lin_b  = (const float*)d_in[6];   // [8192]

    const int E = in_sizes[1] / 2;
    const int* row = eidx;
    const int* col = eidx + E;
    float* ws  = (float*)d_ws;
    float* out = (float*)d_out;

    k0_zero   <<<(WS_ZERO / 4 + 1023) / 1024, 1024, 0, stream>>>((float4*)ws);
    k1_u_deg  <<<256, 1024, 0, stream>>>(lin_w, att, row, E, ws);
    k15_dinv  <<<8,   1024, 0, stream>>>(ws);
    k2_adv_t_xu<<<256, 1024, 0, stream>>>(x, row, col, E, ws);
    k3_s_c0   <<<257, 1024, 0, stream>>>(weight, att, lin_b, ws);
    k4_out    <<<1,   1024, 0, stream>>>(bias, ws, out);
}